// Round 19
// baseline (182.629 us; speedup 1.0000x reference)
//
#include <hip/hip_runtime.h>

typedef __attribute__((ext_vector_type(8))) short short8v;
typedef __attribute__((ext_vector_type(4))) float f32x4;

#define INVLN2 1.4426950408889634f

__device__ __forceinline__ ushort f2bf(float f) {
  union { float f; unsigned int u; } c; c.f = f;
  return (ushort)((c.u + 0x7FFFu + ((c.u >> 16) & 1u)) >> 16);
}

__device__ __forceinline__ unsigned cvtpk(float a, float b) {
  unsigned r;
  asm("v_cvt_pk_bf16_f32 %0, %1, %2" : "=v"(r) : "v"(a), "v"(b));
  return r;
}

__device__ __forceinline__ float exp2w(float x) {
#if __has_builtin(__builtin_amdgcn_exp2f)
  return __builtin_amdgcn_exp2f(x);
#else
  return __expf(x * 0.6931471805599453f);
#endif
}

__device__ __forceinline__ short8v bits8(unsigned a, unsigned b, unsigned c, unsigned d) {
  union { unsigned u[4]; short8v s; } cv;
  cv.u[0] = a; cv.u[1] = b; cv.u[2] = c; cv.u[3] = d;
  return cv.s;
}

// ---- setup: bf16 weights (q rows pre-scaled by qs*INVLN2), scaled qkv bias,
// gathered rel-pos bias (*INVLN2). proj_w columns PRE-PERMUTED by
// kappa(j) = 32h + 16b + 4g + d (zero-shuffle scheme, verified r12-r18).
__global__ __launch_bounds__(256) void setup_k(
    const float* __restrict__ qkv_w, const float* __restrict__ proj_w,
    const float* __restrict__ bias_table, const int* __restrict__ rel_idx,
    const float* __restrict__ qkv_b,
    ushort* __restrict__ qkv_wb, ushort* __restrict__ proj_wb,
    float* __restrict__ bias_comb, float* __restrict__ qkv_bs) {
  const float qs = 0.17677669529663687f * INVLN2;  // 1/sqrt(32) * 1/ln2
  int idx = blockIdx.x * 256 + threadIdx.x;
  if (idx < 27648) {                       // 288*96 (rows 0..95 = q)
    qkv_wb[idx] = f2bf(qkv_w[idx] * (idx < 9216 ? qs : 1.0f));
  } else if (idx < 36864) {                // + 96*96, column-permuted by kappa
    int i = idx - 27648;
    int cw = i / 96, j = i % 96;
    int h = j >> 5, kk = j & 31;
    int g = kk >> 3, b = (kk & 4) >> 2, d = kk & 3;
    int src = h * 32 + 16 * b + 4 * g + d;
    proj_wb[i] = f2bf(proj_w[cw * 96 + src]);
  } else if (idx < 49152) {                // + 3*64*64
    int i = idx - 36864;
    int h = i / 4096, rc = i % 4096;
    bias_comb[i] = bias_table[rel_idx[rc] * 3 + h] * INVLN2;
  } else if (idx < 49440) {                // + 288 scaled qkv bias
    int i = idx - 49152;
    qkv_bs[i] = qkv_b[i] * (i < 96 ? qs : 1.0f);
  }
}

// ---- main fused kernel: TWO windows per block {bb, bb+4096} (r12 verified
// structure) + qkv weights staged into LDS (r14 verified component).
// LDS = 26624 (klds) + 24576 (vts) + 29952 (wq) = 81152 B -> 2 blocks/CU:
// two INDEPENDENT blocks per CU destagger (no inter-block barriers) and
// cover each other's per-wave ds_read/global latency — the one overlap
// configuration not yet tested with all amortizations in place.
__global__ __launch_bounds__(256, 2) void winattn(
    const float* __restrict__ x, const float* __restrict__ mask,
    const ushort* __restrict__ qkv_wb, const ushort* __restrict__ proj_wb,
    const float* __restrict__ bias_comb, const float* __restrict__ qkv_bs,
    const float* __restrict__ proj_b, float* __restrict__ out) {
  __shared__ ushort klds[2][64][104];  // k [token][chan-slot] (write-once)
  __shared__ ushort vts[2][96][64];    // v^T [chan][token-slot], XOR-swizzled
  __shared__ ushort wq[29952];         // qkv weights [288][104-padded]

  const int bb = blockIdx.x;           // 0..4095
  const int t = threadIdx.x;
  const int w = t >> 6;
  const int lane = t & 63;
  const int l15 = lane & 15;
  const int g = lane >> 4;
  const int qrow = w * 16 + l15;       // this lane's q-token (all phases)

  // ---- issue ALL HBM-latency loads first: x (12x16B) + mask (4x16B)
  float4 xr4[2][3][2];
  #pragma unroll
  for (int u = 0; u < 2; ++u) {
    const float* xr = x + ((size_t)(bb + u * 4096) * 64 + qrow) * 96 + g * 8;
    #pragma unroll
    for (int ks3 = 0; ks3 < 3; ++ks3) {
      xr4[u][ks3][0] = *reinterpret_cast<const float4*>(xr + ks3 * 32);
      xr4[u][ks3][1] = *reinterpret_cast<const float4*>(xr + ks3 * 32 + 4);
    }
  }
  const float* mrow = mask + (size_t)bb * 4096 + qrow * 64;
  float4 mk4[4];
  #pragma unroll
  for (int tj = 0; tj < 4; ++tj)
    mk4[tj] = *reinterpret_cast<const float4*>(mrow + tj * 16 + g * 4);

  // ---- stage qkv weights into LDS (once per block, shared by 4 waves).
  #pragma unroll
  for (int i = 0; i < 14; ++i) {
    const int c = i * 256 + t;
    if (i < 13 || t < 128) {
      const int row = c / 12, cc = c % 12;
      short8v wv = *reinterpret_cast<const short8v*>(qkv_wb + row * 96 + cc * 8);
      *reinterpret_cast<short8v*>(&wq[row * 104 + cc * 8]) = wv;
    }
  }
  __syncthreads();   // weights published

  // x -> bf16 A-fragments
  short8v xa[2][3];
  #pragma unroll
  for (int u = 0; u < 2; ++u)
    #pragma unroll
    for (int ks3 = 0; ks3 < 3; ++ks3) {
      const float4 a0 = xr4[u][ks3][0], a1 = xr4[u][ks3][1];
      xa[u][ks3] = bits8(cvtpk(a0.x, a0.y), cvtpk(a0.z, a0.w),
                         cvtpk(a1.x, a1.y), cvtpk(a1.z, a1.w));
    }

  // ---- QKV GEMM, merged nt=0..17 loop, 1-ahead weight prefetch from LDS.
  unsigned qpk[2][6][2];
  short8v bfA[3];
  float4 qbA = {0.f, 0.f, 0.f, 0.f}, qbB;
  float vbA = 0.f, vbB;
  {
    const ushort* wr = &wq[l15 * 104 + g * 8];
    bfA[0] = *reinterpret_cast<const short8v*>(wr);
    bfA[1] = *reinterpret_cast<const short8v*>(wr + 32);
    bfA[2] = *reinterpret_cast<const short8v*>(wr + 64);
    qbA = *reinterpret_cast<const float4*>(qkv_bs + g * 4);
  }
  #pragma unroll
  for (int nt = 0; nt < 18; ++nt) {
    short8v bfB[3];
    if (nt < 17) {   // prefetch next iteration's weights (LDS) + bias (L2)
      const ushort* wr = &wq[((nt + 1) * 16 + l15) * 104 + g * 8];
      bfB[0] = *reinterpret_cast<const short8v*>(wr);
      bfB[1] = *reinterpret_cast<const short8v*>(wr + 32);
      bfB[2] = *reinterpret_cast<const short8v*>(wr + 64);
      if (nt + 1 < 12) qbB = *reinterpret_cast<const float4*>(qkv_bs + (nt + 1) * 16 + g * 4);
      else             vbB = qkv_bs[(nt + 1) * 16 + l15];
    }
    if (nt < 6) {                       // q (swapped mfma -> token-local D)
      #pragma unroll
      for (int u = 0; u < 2; ++u) {
        f32x4 acc = {0.f, 0.f, 0.f, 0.f};
        #pragma unroll
        for (int ks3 = 0; ks3 < 3; ++ks3)
          acc = __builtin_amdgcn_mfma_f32_16x16x32_bf16(bfA[ks3], xa[u][ks3], acc, 0, 0, 0);
        qpk[u][nt][0] = cvtpk(acc[0] + qbA.x, acc[1] + qbA.y);
        qpk[u][nt][1] = cvtpk(acc[2] + qbA.z, acc[3] + qbA.w);
      }
    } else if (nt < 12) {               // k (swapped) -> klds, permuted slot
      const int m = nt - 6;
      const int kcol = 32 * (m >> 1) + 8 * g + 4 * (m & 1);  // sigma base
      #pragma unroll
      for (int u = 0; u < 2; ++u) {
        f32x4 acc = {0.f, 0.f, 0.f, 0.f};
        #pragma unroll
        for (int ks3 = 0; ks3 < 3; ++ks3)
          acc = __builtin_amdgcn_mfma_f32_16x16x32_bf16(bfA[ks3], xa[u][ks3], acc, 0, 0, 0);
        uint2 pk = make_uint2(cvtpk(acc[0] + qbA.x, acc[1] + qbA.y),
                              cvtpk(acc[2] + qbA.z, acc[3] + qbA.w));
        *reinterpret_cast<uint2*>(&klds[u][qrow][kcol]) = pk;
      }
    } else {                            // v -> vts, permuted token slot + XOR
      const int vc = nt * 16 + l15 - 192;
      const int tk = (32 * (w >> 1) + 8 * g + 4 * (w & 1)) ^ ((vc & 7) << 3);
      #pragma unroll
      for (int u = 0; u < 2; ++u) {
        f32x4 acc = {0.f, 0.f, 0.f, 0.f};
        #pragma unroll
        for (int ks3 = 0; ks3 < 3; ++ks3)
          acc = __builtin_amdgcn_mfma_f32_16x16x32_bf16(xa[u][ks3], bfA[ks3], acc, 0, 0, 0);
        uint2 pk = make_uint2(cvtpk(acc[0] + vbA, acc[1] + vbA),
                              cvtpk(acc[2] + vbA, acc[3] + vbA));
        *reinterpret_cast<uint2*>(&vts[u][vc][tk]) = pk;
      }
    }
    if (nt < 17) {
      bfA[0] = bfB[0]; bfA[1] = bfB[1]; bfA[2] = bfB[2];
      qbA = qbB; vbA = vbB;
    }
  }

  // q -> QK^T B-fragments: pure lane-local pack (zero-shuffle)
  short8v qf[2][3];
  #pragma unroll
  for (int u = 0; u < 2; ++u)
    #pragma unroll
    for (int h = 0; h < 3; ++h)
      qf[u][h] = bits8(qpk[u][2 * h][0], qpk[u][2 * h][1],
                       qpk[u][2 * h + 1][0], qpk[u][2 * h + 1][1]);

  // ---- hoist rel-pos bias loads (L2), fold mask: bmk[h][tj][r]
  const float* bcb0 = bias_comb + qrow * 64;
  float bmk[3][4][4];
  #pragma unroll
  for (int h = 0; h < 3; ++h)
    #pragma unroll
    for (int tj = 0; tj < 4; ++tj) {
      float4 b4 = *reinterpret_cast<const float4*>(bcb0 + h * 4096 + tj * 16 + g * 4);
      bmk[h][tj][0] = b4.x + mk4[tj].x * INVLN2;
      bmk[h][tj][1] = b4.y + mk4[tj].y * INVLN2;
      bmk[h][tj][2] = b4.z + mk4[tj].z * INVLN2;
      bmk[h][tj][3] = b4.w + mk4[tj].w * INVLN2;
    }

  __syncthreads();   // publish klds + vts

  short8v ofv[3][2];   // per-head normalized O A-fragments (lane-local pack)

  #pragma unroll
  for (int h = 0; h < 3; ++h) {
    // QK^T swapped: lane holds S[q=qrow][k=tj*16+g*4+r] (in exp2 domain)
    f32x4 s[2][4];
    #pragma unroll
    for (int tj = 0; tj < 4; ++tj) {
      #pragma unroll
      for (int u = 0; u < 2; ++u) {
        short8v kf = *reinterpret_cast<const short8v*>(&klds[u][tj * 16 + l15][h * 32 + g * 8]);
        f32x4 z = {0.f, 0.f, 0.f, 0.f};
        s[u][tj] = __builtin_amdgcn_mfma_f32_16x16x32_bf16(kf, qf[u][h], z, 0, 0, 0);
      }
    }
    // + (bias+mask) pre-combined in regs; exp2; row-sum
    #pragma unroll
    for (int tj = 0; tj < 4; ++tj)
      #pragma unroll
      for (int u = 0; u < 2; ++u)
        #pragma unroll
        for (int r = 0; r < 4; ++r) s[u][tj][r] += bmk[h][tj][r];
    float inv[2];
    #pragma unroll
    for (int u = 0; u < 2; ++u) {
      #pragma unroll
      for (int tj = 0; tj < 4; ++tj)
        #pragma unroll
        for (int r = 0; r < 4; ++r) s[u][tj][r] = exp2w(s[u][tj][r]);
      float sm = ((s[u][0][0] + s[u][0][1]) + (s[u][0][2] + s[u][0][3]))
               + ((s[u][1][0] + s[u][1][1]) + (s[u][1][2] + s[u][1][3]))
               + ((s[u][2][0] + s[u][2][1]) + (s[u][2][2] + s[u][2][3]))
               + ((s[u][3][0] + s[u][3][1]) + (s[u][3][2] + s[u][3][3]));
      sm += __shfl_xor(sm, 16);
      sm += __shfl_xor(sm, 32);
      inv[u] = __builtin_amdgcn_rcpf(sm);
    }
    // P -> PV B-fragments: pure lane-local pack (token order = vts slots)
    short8v pfv[2][2];
    #pragma unroll
    for (int u = 0; u < 2; ++u) {
      unsigned p00 = cvtpk(s[u][0][0], s[u][0][1]);
      unsigned p01 = cvtpk(s[u][0][2], s[u][0][3]);
      unsigned p10 = cvtpk(s[u][1][0], s[u][1][1]);
      unsigned p11 = cvtpk(s[u][1][2], s[u][1][3]);
      unsigned p20 = cvtpk(s[u][2][0], s[u][2][1]);
      unsigned p21 = cvtpk(s[u][2][2], s[u][2][3]);
      unsigned p30 = cvtpk(s[u][3][0], s[u][3][1]);
      unsigned p31 = cvtpk(s[u][3][2], s[u][3][3]);
      pfv[u][0] = bits8(p00, p01, p10, p11);
      pfv[u][1] = bits8(p20, p21, p30, p31);
    }
    // PV swapped: O[q=qrow][d] (swizzled vts reads)
    #pragma unroll
    for (int u = 0; u < 2; ++u) {
      f32x4 oacc[2];
      #pragma unroll
      for (int nt = 0; nt < 2; ++nt) {
        const int vc = h * 32 + nt * 16 + l15;
        f32x4 o = {0.f, 0.f, 0.f, 0.f};
        #pragma unroll
        for (int ks2 = 0; ks2 < 2; ++ks2) {
          const int tk = (ks2 * 32 + g * 8) ^ ((vc & 7) << 3);
          short8v vf = *reinterpret_cast<const short8v*>(&vts[u][vc][tk]);
          o = __builtin_amdgcn_mfma_f32_16x16x32_bf16(vf, pfv[u][ks2], o, 0, 0, 0);
        }
        oacc[nt] = o;
      }
      // normalize+pack O -> proj A-fragment (proj_wb pre-permuted)
      unsigned o00 = cvtpk(oacc[0][0] * inv[u], oacc[0][1] * inv[u]);
      unsigned o01 = cvtpk(oacc[0][2] * inv[u], oacc[0][3] * inv[u]);
      unsigned o10 = cvtpk(oacc[1][0] * inv[u], oacc[1][1] * inv[u]);
      unsigned o11 = cvtpk(oacc[1][2] * inv[u], oacc[1][3] * inv[u]);
      ofv[h][u] = bits8(o00, o01, o10, o11);
    }
  }

  // output projection (all heads): pacc[u][nt2] = sum_h O_h @ Wp_h
  f32x4 pacc[2][6];
  #pragma unroll
  for (int u = 0; u < 2; ++u)
    #pragma unroll
    for (int nt2 = 0; nt2 < 6; ++nt2) pacc[u][nt2] = (f32x4){0.f, 0.f, 0.f, 0.f};
  #pragma unroll
  for (int h = 0; h < 3; ++h) {
    #pragma unroll
    for (int nt2 = 0; nt2 < 6; ++nt2) {
      short8v pfw = *reinterpret_cast<const short8v*>(proj_wb + (nt2 * 16 + l15) * 96 + h * 32 + g * 8);
      #pragma unroll
      for (int u = 0; u < 2; ++u)
        pacc[u][nt2] = __builtin_amdgcn_mfma_f32_16x16x32_bf16(ofv[h][u], pfw, pacc[u][nt2], 0, 0, 0);
    }
  }

  // epilogue: + proj bias, f32 stores for both windows
  float pb[6];
  #pragma unroll
  for (int nt2 = 0; nt2 < 6; ++nt2) pb[nt2] = proj_b[nt2 * 16 + l15];
  #pragma unroll
  for (int u = 0; u < 2; ++u) {
    float* ob = out + (size_t)(bb + u * 4096) * 6144 + (w * 16 + g * 4) * 96 + l15;
    #pragma unroll
    for (int nt2 = 0; nt2 < 6; ++nt2)
      #pragma unroll
      for (int r = 0; r < 4; ++r)
        ob[r * 96 + nt2 * 16] = pacc[u][nt2][r] + pb[nt2];
  }
}

extern "C" void kernel_launch(void* const* d_in, const int* in_sizes, int n_in,
                              void* d_out, int out_size, void* d_ws, size_t ws_size,
                              hipStream_t stream) {
  const float* x          = (const float*)d_in[0];
  const float* mask       = (const float*)d_in[1];
  const float* qkv_w      = (const float*)d_in[2];
  const float* qkv_b      = (const float*)d_in[3];
  const float* proj_w     = (const float*)d_in[4];
  const float* proj_b     = (const float*)d_in[5];
  const float* bias_table = (const float*)d_in[6];
  const int*   rel_idx    = (const int*)d_in[7];

  char* ws = (char*)d_ws;
  ushort* qkv_wb    = (ushort*)ws;                    // 288*96*2 = 55296 B
  ushort* proj_wb   = (ushort*)(ws + 55296);          // 96*96*2  = 18432 B
  float*  bias_comb = (float*)(ws + 55296 + 18432);   // 3*64*64*4 = 49152 B
  float*  qkv_bs    = (float*)(ws + 55296 + 18432 + 49152);  // 288*4 = 1152 B

  setup_k<<<194, 256, 0, stream>>>(qkv_w, proj_w, bias_table, rel_idx, qkv_b,
                                   qkv_wb, proj_wb, bias_comb, qkv_bs);
  winattn<<<4096, 256, 0, stream>>>(x, mask, qkv_wb, proj_wb,
                                    bias_comb, qkv_bs, proj_b, (float*)d_out);
}

// Round 20
// 160.192 us; speedup vs baseline: 1.1401x; 1.1401x over previous
//
#include <hip/hip_runtime.h>

typedef __attribute__((ext_vector_type(8))) short short8v;
typedef __attribute__((ext_vector_type(4))) float f32x4;

#define INVLN2 1.4426950408889634f

__device__ __forceinline__ ushort f2bf(float f) {
  union { float f; unsigned int u; } c; c.f = f;
  return (ushort)((c.u + 0x7FFFu + ((c.u >> 16) & 1u)) >> 16);
}

__device__ __forceinline__ unsigned cvtpk(float a, float b) {
  unsigned r;
  asm("v_cvt_pk_bf16_f32 %0, %1, %2" : "=v"(r) : "v"(a), "v"(b));
  return r;
}

__device__ __forceinline__ float exp2w(float x) {
#if __has_builtin(__builtin_amdgcn_exp2f)
  return __builtin_amdgcn_exp2f(x);
#else
  return __expf(x * 0.6931471805599453f);
#endif
}

__device__ __forceinline__ short8v bits8(unsigned a, unsigned b, unsigned c, unsigned d) {
  union { unsigned u[4]; short8v s; } cv;
  cv.u[0] = a; cv.u[1] = b; cv.u[2] = c; cv.u[3] = d;
  return cv.s;
}

// ---- setup: bf16 weights (q rows pre-scaled by qs*INVLN2), scaled qkv bias,
// gathered rel-pos bias (*INVLN2). proj_w columns PRE-PERMUTED by
// kappa(j) = 32h + 16b + 4g + d so the runtime proj B-fragment k-order
// matches the lane-local O k-order (zero-shuffle scheme, verified r12-r18).
__global__ __launch_bounds__(256) void setup_k(
    const float* __restrict__ qkv_w, const float* __restrict__ proj_w,
    const float* __restrict__ bias_table, const int* __restrict__ rel_idx,
    const float* __restrict__ qkv_b,
    ushort* __restrict__ qkv_wb, ushort* __restrict__ proj_wb,
    float* __restrict__ bias_comb, float* __restrict__ qkv_bs) {
  const float qs = 0.17677669529663687f * INVLN2;  // 1/sqrt(32) * 1/ln2
  int idx = blockIdx.x * 256 + threadIdx.x;
  if (idx < 27648) {                       // 288*96 (rows 0..95 = q)
    qkv_wb[idx] = f2bf(qkv_w[idx] * (idx < 9216 ? qs : 1.0f));
  } else if (idx < 36864) {                // + 96*96, column-permuted by kappa
    int i = idx - 27648;
    int cw = i / 96, j = i % 96;
    int h = j >> 5, kk = j & 31;
    int g = kk >> 3, b = (kk & 4) >> 2, d = kk & 3;
    int src = h * 32 + 16 * b + 4 * g + d;
    proj_wb[i] = f2bf(proj_w[cw * 96 + src]);
  } else if (idx < 49152) {                // + 3*64*64
    int i = idx - 36864;
    int h = i / 4096, rc = i % 4096;
    bias_comb[i] = bias_table[rel_idx[rc] * 3 + h] * INVLN2;
  } else if (idx < 49440) {                // + 288 scaled qkv bias
    int i = idx - 49152;
    qkv_bs[i] = qkv_b[i] * (i < 96 ? qs : 1.0f);
  }
}

// ---- main fused kernel: FOUR windows per block {bb, bb+4096, bb+2048,
// bb+6144} (zero-shuffle fragment scheme) + qkv weights staged into LDS once
// per block (rows padded 96->104: 2-way bank aliasing = free).
// LDS = 53248 (klds) + 49152 (vts) + 59904 (wq) = 162304 B -> 1 block/CU.
// [FINAL: best verified configuration of the session, 159.7 us @ r18.]
__global__ __launch_bounds__(256, 1) void winattn(
    const float* __restrict__ x, const float* __restrict__ mask,
    const ushort* __restrict__ qkv_wb, const ushort* __restrict__ proj_wb,
    const float* __restrict__ bias_comb, const float* __restrict__ qkv_bs,
    const float* __restrict__ proj_b, float* __restrict__ out) {
  __shared__ ushort klds[4][64][104];  // k [token][chan-slot] (write-once)
  __shared__ ushort vts[4][96][64];    // v^T [chan][token-slot], XOR-swizzled
  __shared__ ushort wq[29952];         // qkv weights [288][104-padded]

  const int bb = blockIdx.x;           // 0..2047
  const int t = threadIdx.x;
  const int w = t >> 6;
  const int lane = t & 63;
  const int l15 = lane & 15;
  const int g = lane >> 4;
  const int qrow = w * 16 + l15;       // this lane's q-token (all phases)

  // ---- issue ALL HBM-latency loads first: x (24x16B) + mask (8x16B)
  float4 xr4[4][3][2];
  #pragma unroll
  for (int u = 0; u < 4; ++u) {
    const int win = bb + ((u >> 1) << 11) + ((u & 1) << 12);
    const float* xr = x + ((size_t)win * 64 + qrow) * 96 + g * 8;
    #pragma unroll
    for (int ks3 = 0; ks3 < 3; ++ks3) {
      xr4[u][ks3][0] = *reinterpret_cast<const float4*>(xr + ks3 * 32);
      xr4[u][ks3][1] = *reinterpret_cast<const float4*>(xr + ks3 * 32 + 4);
    }
  }
  float4 mk4[2][4];
  #pragma unroll
  for (int p = 0; p < 2; ++p) {
    const float* mrow = mask + (size_t)(bb + (p << 11)) * 4096 + qrow * 64;
    #pragma unroll
    for (int tj = 0; tj < 4; ++tj)
      mk4[p][tj] = *reinterpret_cast<const float4*>(mrow + tj * 16 + g * 4);
  }

  // ---- stage qkv weights into LDS (once per block, shared by 4 waves).
  #pragma unroll
  for (int i = 0; i < 14; ++i) {
    const int c = i * 256 + t;
    if (i < 13 || t < 128) {
      const int row = c / 12, cc = c % 12;
      short8v wv = *reinterpret_cast<const short8v*>(qkv_wb + row * 96 + cc * 8);
      *reinterpret_cast<short8v*>(&wq[row * 104 + cc * 8]) = wv;
    }
  }
  __syncthreads();   // weights published

  // x -> bf16 A-fragments
  short8v xa[4][3];
  #pragma unroll
  for (int u = 0; u < 4; ++u)
    #pragma unroll
    for (int ks3 = 0; ks3 < 3; ++ks3) {
      const float4 a0 = xr4[u][ks3][0], a1 = xr4[u][ks3][1];
      xa[u][ks3] = bits8(cvtpk(a0.x, a0.y), cvtpk(a0.z, a0.w),
                         cvtpk(a1.x, a1.y), cvtpk(a1.z, a1.w));
    }

  // ---- QKV GEMM, merged nt=0..17 loop, 1-ahead weight prefetch from LDS.
  unsigned qpk[4][6][2];
  short8v bfA[3];
  float4 qbA = {0.f, 0.f, 0.f, 0.f}, qbB;
  float vbA = 0.f, vbB;
  {
    const ushort* wr = &wq[l15 * 104 + g * 8];
    bfA[0] = *reinterpret_cast<const short8v*>(wr);
    bfA[1] = *reinterpret_cast<const short8v*>(wr + 32);
    bfA[2] = *reinterpret_cast<const short8v*>(wr + 64);
    qbA = *reinterpret_cast<const float4*>(qkv_bs + g * 4);
  }
  #pragma unroll
  for (int nt = 0; nt < 18; ++nt) {
    short8v bfB[3];
    if (nt < 17) {   // prefetch next iteration's weights (LDS) + bias (L2)
      const ushort* wr = &wq[((nt + 1) * 16 + l15) * 104 + g * 8];
      bfB[0] = *reinterpret_cast<const short8v*>(wr);
      bfB[1] = *reinterpret_cast<const short8v*>(wr + 32);
      bfB[2] = *reinterpret_cast<const short8v*>(wr + 64);
      if (nt + 1 < 12) qbB = *reinterpret_cast<const float4*>(qkv_bs + (nt + 1) * 16 + g * 4);
      else             vbB = qkv_bs[(nt + 1) * 16 + l15];
    }
    if (nt < 6) {                       // q (swapped mfma -> token-local D)
      #pragma unroll
      for (int u = 0; u < 4; ++u) {
        f32x4 acc = {0.f, 0.f, 0.f, 0.f};
        #pragma unroll
        for (int ks3 = 0; ks3 < 3; ++ks3)
          acc = __builtin_amdgcn_mfma_f32_16x16x32_bf16(bfA[ks3], xa[u][ks3], acc, 0, 0, 0);
        qpk[u][nt][0] = cvtpk(acc[0] + qbA.x, acc[1] + qbA.y);
        qpk[u][nt][1] = cvtpk(acc[2] + qbA.z, acc[3] + qbA.w);
      }
    } else if (nt < 12) {               // k (swapped) -> klds, permuted slot
      const int m = nt - 6;
      const int kcol = 32 * (m >> 1) + 8 * g + 4 * (m & 1);  // sigma base
      #pragma unroll
      for (int u = 0; u < 4; ++u) {
        f32x4 acc = {0.f, 0.f, 0.f, 0.f};
        #pragma unroll
        for (int ks3 = 0; ks3 < 3; ++ks3)
          acc = __builtin_amdgcn_mfma_f32_16x16x32_bf16(bfA[ks3], xa[u][ks3], acc, 0, 0, 0);
        uint2 pk = make_uint2(cvtpk(acc[0] + qbA.x, acc[1] + qbA.y),
                              cvtpk(acc[2] + qbA.z, acc[3] + qbA.w));
        *reinterpret_cast<uint2*>(&klds[u][qrow][kcol]) = pk;
      }
    } else {                            // v -> vts, permuted token slot + XOR
      const int vc = nt * 16 + l15 - 192;
      const int tk = (32 * (w >> 1) + 8 * g + 4 * (w & 1)) ^ ((vc & 7) << 3);
      #pragma unroll
      for (int u = 0; u < 4; ++u) {
        f32x4 acc = {0.f, 0.f, 0.f, 0.f};
        #pragma unroll
        for (int ks3 = 0; ks3 < 3; ++ks3)
          acc = __builtin_amdgcn_mfma_f32_16x16x32_bf16(xa[u][ks3], bfA[ks3], acc, 0, 0, 0);
        uint2 pk = make_uint2(cvtpk(acc[0] + vbA, acc[1] + vbA),
                              cvtpk(acc[2] + vbA, acc[3] + vbA));
        *reinterpret_cast<uint2*>(&vts[u][vc][tk]) = pk;
      }
    }
    if (nt < 17) {
      bfA[0] = bfB[0]; bfA[1] = bfB[1]; bfA[2] = bfB[2];
      qbA = qbB; vbA = vbB;
    }
  }

  // q -> QK^T B-fragments: pure lane-local pack (zero-shuffle)
  short8v qf[4][3];
  #pragma unroll
  for (int u = 0; u < 4; ++u)
    #pragma unroll
    for (int h = 0; h < 3; ++h)
      qf[u][h] = bits8(qpk[u][2 * h][0], qpk[u][2 * h][1],
                       qpk[u][2 * h + 1][0], qpk[u][2 * h + 1][1]);

  // ---- hoist rel-pos bias loads (L2): bcf[h][tj][r] (shared by all u);
  // mask kept per-pair, combined per-head below.
  const float* bcb0 = bias_comb + qrow * 64;
  float bcf[3][4][4];
  #pragma unroll
  for (int h = 0; h < 3; ++h)
    #pragma unroll
    for (int tj = 0; tj < 4; ++tj) {
      float4 b4 = *reinterpret_cast<const float4*>(bcb0 + h * 4096 + tj * 16 + g * 4);
      bcf[h][tj][0] = b4.x; bcf[h][tj][1] = b4.y;
      bcf[h][tj][2] = b4.z; bcf[h][tj][3] = b4.w;
    }
  float mkp[2][4][4];
  #pragma unroll
  for (int p = 0; p < 2; ++p)
    #pragma unroll
    for (int tj = 0; tj < 4; ++tj) {
      mkp[p][tj][0] = mk4[p][tj].x * INVLN2;
      mkp[p][tj][1] = mk4[p][tj].y * INVLN2;
      mkp[p][tj][2] = mk4[p][tj].z * INVLN2;
      mkp[p][tj][3] = mk4[p][tj].w * INVLN2;
    }

  __syncthreads();   // publish klds + vts

  short8v ofv[3][4];   // per-head normalized O A-fragments (lane-local pack)

  #pragma unroll
  for (int h = 0; h < 3; ++h) {
    // QK^T swapped: lane holds S[q=qrow][k=tj*16+g*4+r] (in exp2 domain)
    f32x4 s[4][4];
    #pragma unroll
    for (int tj = 0; tj < 4; ++tj) {
      #pragma unroll
      for (int u = 0; u < 4; ++u) {
        short8v kf = *reinterpret_cast<const short8v*>(&klds[u][tj * 16 + l15][h * 32 + g * 8]);
        f32x4 z = {0.f, 0.f, 0.f, 0.f};
        s[u][tj] = __builtin_amdgcn_mfma_f32_16x16x32_bf16(kf, qf[u][h], z, 0, 0, 0);
      }
    }
    // + (bias + mask) [exp2 domain]; exp2; row-sum
    #pragma unroll
    for (int tj = 0; tj < 4; ++tj)
      #pragma unroll
      for (int r = 0; r < 4; ++r) {
        const float b0 = bcf[h][tj][r] + mkp[0][tj][r];
        const float b1 = bcf[h][tj][r] + mkp[1][tj][r];
        s[0][tj][r] += b0; s[1][tj][r] += b0;
        s[2][tj][r] += b1; s[3][tj][r] += b1;
      }
    float inv[4];
    #pragma unroll
    for (int u = 0; u < 4; ++u) {
      #pragma unroll
      for (int tj = 0; tj < 4; ++tj)
        #pragma unroll
        for (int r = 0; r < 4; ++r) s[u][tj][r] = exp2w(s[u][tj][r]);
      float sm = ((s[u][0][0] + s[u][0][1]) + (s[u][0][2] + s[u][0][3]))
               + ((s[u][1][0] + s[u][1][1]) + (s[u][1][2] + s[u][1][3]))
               + ((s[u][2][0] + s[u][2][1]) + (s[u][2][2] + s[u][2][3]))
               + ((s[u][3][0] + s[u][3][1]) + (s[u][3][2] + s[u][3][3]));
      sm += __shfl_xor(sm, 16);
      sm += __shfl_xor(sm, 32);
      inv[u] = __builtin_amdgcn_rcpf(sm);
    }
    // P -> PV B-fragments: pure lane-local pack (token order = vts slots)
    short8v pfv[4][2];
    #pragma unroll
    for (int u = 0; u < 4; ++u) {
      unsigned p00 = cvtpk(s[u][0][0], s[u][0][1]);
      unsigned p01 = cvtpk(s[u][0][2], s[u][0][3]);
      unsigned p10 = cvtpk(s[u][1][0], s[u][1][1]);
      unsigned p11 = cvtpk(s[u][1][2], s[u][1][3]);
      unsigned p20 = cvtpk(s[u][2][0], s[u][2][1]);
      unsigned p21 = cvtpk(s[u][2][2], s[u][2][3]);
      unsigned p30 = cvtpk(s[u][3][0], s[u][3][1]);
      unsigned p31 = cvtpk(s[u][3][2], s[u][3][3]);
      pfv[u][0] = bits8(p00, p01, p10, p11);
      pfv[u][1] = bits8(p20, p21, p30, p31);
    }
    // PV swapped: O[q=qrow][d] (swizzled vts reads)
    #pragma unroll
    for (int u = 0; u < 4; ++u) {
      f32x4 oacc[2];
      #pragma unroll
      for (int nt = 0; nt < 2; ++nt) {
        const int vc = h * 32 + nt * 16 + l15;
        f32x4 o = {0.f, 0.f, 0.f, 0.f};
        #pragma unroll
        for (int ks2 = 0; ks2 < 2; ++ks2) {
          const int tk = (ks2 * 32 + g * 8) ^ ((vc & 7) << 3);
          short8v vf = *reinterpret_cast<const short8v*>(&vts[u][vc][tk]);
          o = __builtin_amdgcn_mfma_f32_16x16x32_bf16(vf, pfv[u][ks2], o, 0, 0, 0);
        }
        oacc[nt] = o;
      }
      // normalize+pack O -> proj A-fragment (proj_wb pre-permuted)
      unsigned o00 = cvtpk(oacc[0][0] * inv[u], oacc[0][1] * inv[u]);
      unsigned o01 = cvtpk(oacc[0][2] * inv[u], oacc[0][3] * inv[u]);
      unsigned o10 = cvtpk(oacc[1][0] * inv[u], oacc[1][1] * inv[u]);
      unsigned o11 = cvtpk(oacc[1][2] * inv[u], oacc[1][3] * inv[u]);
      ofv[h][u] = bits8(o00, o01, o10, o11);
    }
  }

  // output projection (all heads): pacc[u][nt2] = sum_h O_h @ Wp_h
  f32x4 pacc[4][6];
  #pragma unroll
  for (int u = 0; u < 4; ++u)
    #pragma unroll
    for (int nt2 = 0; nt2 < 6; ++nt2) pacc[u][nt2] = (f32x4){0.f, 0.f, 0.f, 0.f};
  #pragma unroll
  for (int h = 0; h < 3; ++h) {
    #pragma unroll
    for (int nt2 = 0; nt2 < 6; ++nt2) {
      short8v pfw = *reinterpret_cast<const short8v*>(proj_wb + (nt2 * 16 + l15) * 96 + h * 32 + g * 8);
      #pragma unroll
      for (int u = 0; u < 4; ++u)
        pacc[u][nt2] = __builtin_amdgcn_mfma_f32_16x16x32_bf16(ofv[h][u], pfw, pacc[u][nt2], 0, 0, 0);
    }
  }

  // epilogue: + proj bias, f32 stores for all four windows
  float pb[6];
  #pragma unroll
  for (int nt2 = 0; nt2 < 6; ++nt2) pb[nt2] = proj_b[nt2 * 16 + l15];
  #pragma unroll
  for (int u = 0; u < 4; ++u) {
    const int win = bb + ((u >> 1) << 11) + ((u & 1) << 12);
    float* ob = out + (size_t)win * 6144 + (w * 16 + g * 4) * 96 + l15;
    #pragma unroll
    for (int nt2 = 0; nt2 < 6; ++nt2)
      #pragma unroll
      for (int r = 0; r < 4; ++r)
        ob[r * 96 + nt2 * 16] = pacc[u][nt2][r] + pb[nt2];
  }
}

extern "C" void kernel_launch(void* const* d_in, const int* in_sizes, int n_in,
                              void* d_out, int out_size, void* d_ws, size_t ws_size,
                              hipStream_t stream) {
  const float* x          = (const float*)d_in[0];
  const float* mask       = (const float*)d_in[1];
  const float* qkv_w      = (const float*)d_in[2];
  const float* qkv_b      = (const float*)d_in[3];
  const float* proj_w     = (const float*)d_in[4];
  const float* proj_b     = (const float*)d_in[5];
  const float* bias_table = (const float*)d_in[6];
  const int*   rel_idx    = (const int*)d_in[7];

  char* ws = (char*)d_ws;
  ushort* qkv_wb    = (ushort*)ws;                    // 288*96*2 = 55296 B
  ushort* proj_wb   = (ushort*)(ws + 55296);          // 96*96*2  = 18432 B
  float*  bias_comb = (float*)(ws + 55296 + 18432);   // 3*64*64*4 = 49152 B
  float*  qkv_bs    = (float*)(ws + 55296 + 18432 + 49152);  // 288*4 = 1152 B

  setup_k<<<194, 256, 0, stream>>>(qkv_w, proj_w, bias_table, rel_idx, qkv_b,
                                   qkv_wb, proj_wb, bias_comb, qkv_bs);
  winattn<<<2048, 256, 0, stream>>>(x, mask, qkv_wb, proj_wb,
                                    bias_comb, qkv_bs, proj_b, (float*)d_out);
}

// Round 21
// 152.908 us; speedup vs baseline: 1.1944x; 1.0476x over previous
//
#include <hip/hip_runtime.h>

typedef __attribute__((ext_vector_type(8))) short short8v;
typedef __attribute__((ext_vector_type(4))) float f32x4;

#define INVLN2 1.4426950408889634f

__device__ __forceinline__ ushort f2bf(float f) {
  union { float f; unsigned int u; } c; c.f = f;
  return (ushort)((c.u + 0x7FFFu + ((c.u >> 16) & 1u)) >> 16);
}

__device__ __forceinline__ unsigned cvtpk(float a, float b) {
  unsigned r;
  asm("v_cvt_pk_bf16_f32 %0, %1, %2" : "=v"(r) : "v"(a), "v"(b));
  return r;
}

__device__ __forceinline__ float exp2w(float x) {
#if __has_builtin(__builtin_amdgcn_exp2f)
  return __builtin_amdgcn_exp2f(x);
#else
  return __expf(x * 0.6931471805599453f);
#endif
}

__device__ __forceinline__ short8v bits8(unsigned a, unsigned b, unsigned c, unsigned d) {
  union { unsigned u[4]; short8v s; } cv;
  cv.u[0] = a; cv.u[1] = b; cv.u[2] = c; cv.u[3] = d;
  return cv.s;
}

// ---- setup: bf16 weights (q rows pre-scaled by qs*INVLN2), scaled qkv bias,
// gathered rel-pos bias (*INVLN2). proj_w columns PRE-PERMUTED by
// kappa(j) = 32h + 16b + 4g + d (zero-shuffle scheme, verified r12-r20).
__global__ __launch_bounds__(256) void setup_k(
    const float* __restrict__ qkv_w, const float* __restrict__ proj_w,
    const float* __restrict__ bias_table, const int* __restrict__ rel_idx,
    const float* __restrict__ qkv_b,
    ushort* __restrict__ qkv_wb, ushort* __restrict__ proj_wb,
    float* __restrict__ bias_comb, float* __restrict__ qkv_bs) {
  const float qs = 0.17677669529663687f * INVLN2;  // 1/sqrt(32) * 1/ln2
  int idx = blockIdx.x * 256 + threadIdx.x;
  if (idx < 27648) {                       // 288*96 (rows 0..95 = q)
    qkv_wb[idx] = f2bf(qkv_w[idx] * (idx < 9216 ? qs : 1.0f));
  } else if (idx < 36864) {                // + 96*96, column-permuted by kappa
    int i = idx - 27648;
    int cw = i / 96, j = i % 96;
    int h = j >> 5, kk = j & 31;
    int g = kk >> 3, b = (kk & 4) >> 2, d = kk & 3;
    int src = h * 32 + 16 * b + 4 * g + d;
    proj_wb[i] = f2bf(proj_w[cw * 96 + src]);
  } else if (idx < 49152) {                // + 3*64*64
    int i = idx - 36864;
    int h = i / 4096, rc = i % 4096;
    bias_comb[i] = bias_table[rel_idx[rc] * 3 + h] * INVLN2;
  } else if (idx < 49440) {                // + 288 scaled qkv bias
    int i = idx - 49152;
    qkv_bs[i] = qkv_b[i] * (i < 96 ? qs : 1.0f);
  }
}

// ---- main fused kernel: FOUR windows per block on EIGHT waves (512 thr).
// Waves 0-3 own windows {bb, bb+4096} (mask row bb); waves 4-7 own
// {bb+2048, bb+6144} (mask row bb+2048). Each wave carries 2 u-streams:
// per-wave critical path HALVES vs r18 while 2 waves/SIMD interleave at
// independent phases (the overlap 1-wave/SIMD structurally forbids).
// Same zero-shuffle math/layouts as r18. LDS = 162304 B -> 1 block/CU.
__global__ __launch_bounds__(512, 2) void winattn(
    const float* __restrict__ x, const float* __restrict__ mask,
    const ushort* __restrict__ qkv_wb, const ushort* __restrict__ proj_wb,
    const float* __restrict__ bias_comb, const float* __restrict__ qkv_bs,
    const float* __restrict__ proj_b, float* __restrict__ out) {
  __shared__ ushort klds[4][64][104];  // k [token][chan-slot] (write-once)
  __shared__ ushort vts[4][96][64];    // v^T [chan][token-slot], XOR-swizzled
  __shared__ ushort wq[29952];         // qkv weights [288][104-padded]

  const int bb = blockIdx.x;           // 0..2047
  const int t = threadIdx.x;
  const int w = t >> 6;                // wave 0..7
  const int grp = w >> 2;              // window group 0/1
  const int wl = w & 3;                // wave-in-group = token block
  const int lane = t & 63;
  const int l15 = lane & 15;
  const int g = lane >> 4;
  const int qrow = wl * 16 + l15;      // this lane's q-token (all phases)

  // this wave's two windows: u = grp*2 + uu
  // win(u) = bb + ((u>>1)<<11) + ((u&1)<<12); mask row = bb + (grp<<11)

  // ---- issue ALL HBM-latency loads first: x (12x16B) + mask (4x16B)
  float4 xr4[2][3][2];
  #pragma unroll
  for (int uu = 0; uu < 2; ++uu) {
    const int u = grp * 2 + uu;
    const int win = bb + ((u >> 1) << 11) + ((u & 1) << 12);
    const float* xr = x + ((size_t)win * 64 + qrow) * 96 + g * 8;
    #pragma unroll
    for (int ks3 = 0; ks3 < 3; ++ks3) {
      xr4[uu][ks3][0] = *reinterpret_cast<const float4*>(xr + ks3 * 32);
      xr4[uu][ks3][1] = *reinterpret_cast<const float4*>(xr + ks3 * 32 + 4);
    }
  }
  const float* mrow = mask + (size_t)(bb + (grp << 11)) * 4096 + qrow * 64;
  float4 mk4[4];
  #pragma unroll
  for (int tj = 0; tj < 4; ++tj)
    mk4[tj] = *reinterpret_cast<const float4*>(mrow + tj * 16 + g * 4);

  // ---- stage qkv weights into LDS (once per block, shared by 8 waves).
  // 288 rows x 12 b128-chunks = 3456 chunks; 512 threads x 6.75 iters.
  #pragma unroll
  for (int i = 0; i < 7; ++i) {
    const int c = i * 512 + t;
    if (i < 6 || t < 384) {
      const int row = c / 12, cc = c % 12;
      short8v wv = *reinterpret_cast<const short8v*>(qkv_wb + row * 96 + cc * 8);
      *reinterpret_cast<short8v*>(&wq[row * 104 + cc * 8]) = wv;
    }
  }
  __syncthreads();   // weights published

  // x -> bf16 A-fragments
  short8v xa[2][3];
  #pragma unroll
  for (int uu = 0; uu < 2; ++uu)
    #pragma unroll
    for (int ks3 = 0; ks3 < 3; ++ks3) {
      const float4 a0 = xr4[uu][ks3][0], a1 = xr4[uu][ks3][1];
      xa[uu][ks3] = bits8(cvtpk(a0.x, a0.y), cvtpk(a0.z, a0.w),
                          cvtpk(a1.x, a1.y), cvtpk(a1.z, a1.w));
    }

  // ---- QKV GEMM, merged nt=0..17 loop, 1-ahead weight prefetch from LDS.
  unsigned qpk[2][6][2];
  short8v bfA[3];
  float4 qbA = {0.f, 0.f, 0.f, 0.f}, qbB;
  float vbA = 0.f, vbB;
  {
    const ushort* wr = &wq[l15 * 104 + g * 8];
    bfA[0] = *reinterpret_cast<const short8v*>(wr);
    bfA[1] = *reinterpret_cast<const short8v*>(wr + 32);
    bfA[2] = *reinterpret_cast<const short8v*>(wr + 64);
    qbA = *reinterpret_cast<const float4*>(qkv_bs + g * 4);
  }
  #pragma unroll
  for (int nt = 0; nt < 18; ++nt) {
    short8v bfB[3];
    if (nt < 17) {   // prefetch next iteration's weights (LDS) + bias (L2)
      const ushort* wr = &wq[((nt + 1) * 16 + l15) * 104 + g * 8];
      bfB[0] = *reinterpret_cast<const short8v*>(wr);
      bfB[1] = *reinterpret_cast<const short8v*>(wr + 32);
      bfB[2] = *reinterpret_cast<const short8v*>(wr + 64);
      if (nt + 1 < 12) qbB = *reinterpret_cast<const float4*>(qkv_bs + (nt + 1) * 16 + g * 4);
      else             vbB = qkv_bs[(nt + 1) * 16 + l15];
    }
    if (nt < 6) {                       // q (swapped mfma -> token-local D)
      #pragma unroll
      for (int uu = 0; uu < 2; ++uu) {
        f32x4 acc = {0.f, 0.f, 0.f, 0.f};
        #pragma unroll
        for (int ks3 = 0; ks3 < 3; ++ks3)
          acc = __builtin_amdgcn_mfma_f32_16x16x32_bf16(bfA[ks3], xa[uu][ks3], acc, 0, 0, 0);
        qpk[uu][nt][0] = cvtpk(acc[0] + qbA.x, acc[1] + qbA.y);
        qpk[uu][nt][1] = cvtpk(acc[2] + qbA.z, acc[3] + qbA.w);
      }
    } else if (nt < 12) {               // k (swapped) -> klds, permuted slot
      const int m = nt - 6;
      const int kcol = 32 * (m >> 1) + 8 * g + 4 * (m & 1);  // sigma base
      #pragma unroll
      for (int uu = 0; uu < 2; ++uu) {
        const int u = grp * 2 + uu;
        f32x4 acc = {0.f, 0.f, 0.f, 0.f};
        #pragma unroll
        for (int ks3 = 0; ks3 < 3; ++ks3)
          acc = __builtin_amdgcn_mfma_f32_16x16x32_bf16(bfA[ks3], xa[uu][ks3], acc, 0, 0, 0);
        uint2 pk = make_uint2(cvtpk(acc[0] + qbA.x, acc[1] + qbA.y),
                              cvtpk(acc[2] + qbA.z, acc[3] + qbA.w));
        *reinterpret_cast<uint2*>(&klds[u][qrow][kcol]) = pk;
      }
    } else {                            // v -> vts, permuted token slot + XOR
      const int vc = nt * 16 + l15 - 192;
      const int tk = (32 * (wl >> 1) + 8 * g + 4 * (wl & 1)) ^ ((vc & 7) << 3);
      #pragma unroll
      for (int uu = 0; uu < 2; ++uu) {
        const int u = grp * 2 + uu;
        f32x4 acc = {0.f, 0.f, 0.f, 0.f};
        #pragma unroll
        for (int ks3 = 0; ks3 < 3; ++ks3)
          acc = __builtin_amdgcn_mfma_f32_16x16x32_bf16(xa[uu][ks3], bfA[ks3], acc, 0, 0, 0);
        uint2 pk = make_uint2(cvtpk(acc[0] + vbA, acc[1] + vbA),
                              cvtpk(acc[2] + vbA, acc[3] + vbA));
        *reinterpret_cast<uint2*>(&vts[u][vc][tk]) = pk;
      }
    }
    if (nt < 17) {
      bfA[0] = bfB[0]; bfA[1] = bfB[1]; bfA[2] = bfB[2];
      qbA = qbB; vbA = vbB;
    }
  }

  // q -> QK^T B-fragments: pure lane-local pack (zero-shuffle)
  short8v qf[2][3];
  #pragma unroll
  for (int uu = 0; uu < 2; ++uu)
    #pragma unroll
    for (int h = 0; h < 3; ++h)
      qf[uu][h] = bits8(qpk[uu][2 * h][0], qpk[uu][2 * h][1],
                        qpk[uu][2 * h + 1][0], qpk[uu][2 * h + 1][1]);

  // ---- hoist rel-pos bias loads (L2), fold mask (single p per wave): bmk
  const float* bcb0 = bias_comb + qrow * 64;
  float bmk[3][4][4];
  #pragma unroll
  for (int h = 0; h < 3; ++h)
    #pragma unroll
    for (int tj = 0; tj < 4; ++tj) {
      float4 b4 = *reinterpret_cast<const float4*>(bcb0 + h * 4096 + tj * 16 + g * 4);
      bmk[h][tj][0] = b4.x + mk4[tj].x * INVLN2;
      bmk[h][tj][1] = b4.y + mk4[tj].y * INVLN2;
      bmk[h][tj][2] = b4.z + mk4[tj].z * INVLN2;
      bmk[h][tj][3] = b4.w + mk4[tj].w * INVLN2;
    }

  __syncthreads();   // publish klds + vts

  short8v ofv[3][2];   // per-head normalized O A-fragments (lane-local pack)

  #pragma unroll
  for (int h = 0; h < 3; ++h) {
    // QK^T swapped: lane holds S[q=qrow][k=tj*16+g*4+r] (in exp2 domain)
    f32x4 s[2][4];
    #pragma unroll
    for (int tj = 0; tj < 4; ++tj) {
      #pragma unroll
      for (int uu = 0; uu < 2; ++uu) {
        const int u = grp * 2 + uu;
        short8v kf = *reinterpret_cast<const short8v*>(&klds[u][tj * 16 + l15][h * 32 + g * 8]);
        f32x4 z = {0.f, 0.f, 0.f, 0.f};
        s[uu][tj] = __builtin_amdgcn_mfma_f32_16x16x32_bf16(kf, qf[uu][h], z, 0, 0, 0);
      }
    }
    // + (bias+mask) pre-combined; exp2; row-sum
    #pragma unroll
    for (int tj = 0; tj < 4; ++tj)
      #pragma unroll
      for (int uu = 0; uu < 2; ++uu)
        #pragma unroll
        for (int r = 0; r < 4; ++r) s[uu][tj][r] += bmk[h][tj][r];
    float inv[2];
    #pragma unroll
    for (int uu = 0; uu < 2; ++uu) {
      #pragma unroll
      for (int tj = 0; tj < 4; ++tj)
        #pragma unroll
        for (int r = 0; r < 4; ++r) s[uu][tj][r] = exp2w(s[uu][tj][r]);
      float sm = ((s[uu][0][0] + s[uu][0][1]) + (s[uu][0][2] + s[uu][0][3]))
               + ((s[uu][1][0] + s[uu][1][1]) + (s[uu][1][2] + s[uu][1][3]))
               + ((s[uu][2][0] + s[uu][2][1]) + (s[uu][2][2] + s[uu][2][3]))
               + ((s[uu][3][0] + s[uu][3][1]) + (s[uu][3][2] + s[uu][3][3]));
      sm += __shfl_xor(sm, 16);
      sm += __shfl_xor(sm, 32);
      inv[uu] = __builtin_amdgcn_rcpf(sm);
    }
    // P -> PV B-fragments: pure lane-local pack (token order = vts slots)
    short8v pfv[2][2];
    #pragma unroll
    for (int uu = 0; uu < 2; ++uu) {
      unsigned p00 = cvtpk(s[uu][0][0], s[uu][0][1]);
      unsigned p01 = cvtpk(s[uu][0][2], s[uu][0][3]);
      unsigned p10 = cvtpk(s[uu][1][0], s[uu][1][1]);
      unsigned p11 = cvtpk(s[uu][1][2], s[uu][1][3]);
      unsigned p20 = cvtpk(s[uu][2][0], s[uu][2][1]);
      unsigned p21 = cvtpk(s[uu][2][2], s[uu][2][3]);
      unsigned p30 = cvtpk(s[uu][3][0], s[uu][3][1]);
      unsigned p31 = cvtpk(s[uu][3][2], s[uu][3][3]);
      pfv[uu][0] = bits8(p00, p01, p10, p11);
      pfv[uu][1] = bits8(p20, p21, p30, p31);
    }
    // PV swapped: O[q=qrow][d] (swizzled vts reads)
    #pragma unroll
    for (int uu = 0; uu < 2; ++uu) {
      const int u = grp * 2 + uu;
      f32x4 oacc[2];
      #pragma unroll
      for (int nt = 0; nt < 2; ++nt) {
        const int vc = h * 32 + nt * 16 + l15;
        f32x4 o = {0.f, 0.f, 0.f, 0.f};
        #pragma unroll
        for (int ks2 = 0; ks2 < 2; ++ks2) {
          const int tk = (ks2 * 32 + g * 8) ^ ((vc & 7) << 3);
          short8v vf = *reinterpret_cast<const short8v*>(&vts[u][vc][tk]);
          o = __builtin_amdgcn_mfma_f32_16x16x32_bf16(vf, pfv[uu][ks2], o, 0, 0, 0);
        }
        oacc[nt] = o;
      }
      // normalize+pack O -> proj A-fragment (proj_wb pre-permuted)
      unsigned o00 = cvtpk(oacc[0][0] * inv[uu], oacc[0][1] * inv[uu]);
      unsigned o01 = cvtpk(oacc[0][2] * inv[uu], oacc[0][3] * inv[uu]);
      unsigned o10 = cvtpk(oacc[1][0] * inv[uu], oacc[1][1] * inv[uu]);
      unsigned o11 = cvtpk(oacc[1][2] * inv[uu], oacc[1][3] * inv[uu]);
      ofv[h][uu] = bits8(o00, o01, o10, o11);
    }
  }

  // output projection (all heads): pacc[uu][nt2] = sum_h O_h @ Wp_h
  f32x4 pacc[2][6];
  #pragma unroll
  for (int uu = 0; uu < 2; ++uu)
    #pragma unroll
    for (int nt2 = 0; nt2 < 6; ++nt2) pacc[uu][nt2] = (f32x4){0.f, 0.f, 0.f, 0.f};
  #pragma unroll
  for (int h = 0; h < 3; ++h) {
    #pragma unroll
    for (int nt2 = 0; nt2 < 6; ++nt2) {
      short8v pfw = *reinterpret_cast<const short8v*>(proj_wb + (nt2 * 16 + l15) * 96 + h * 32 + g * 8);
      #pragma unroll
      for (int uu = 0; uu < 2; ++uu)
        pacc[uu][nt2] = __builtin_amdgcn_mfma_f32_16x16x32_bf16(ofv[h][uu], pfw, pacc[uu][nt2], 0, 0, 0);
    }
  }

  // epilogue: + proj bias, f32 stores for this wave's two windows
  float pb[6];
  #pragma unroll
  for (int nt2 = 0; nt2 < 6; ++nt2) pb[nt2] = proj_b[nt2 * 16 + l15];
  #pragma unroll
  for (int uu = 0; uu < 2; ++uu) {
    const int u = grp * 2 + uu;
    const int win = bb + ((u >> 1) << 11) + ((u & 1) << 12);
    float* ob = out + (size_t)win * 6144 + (wl * 16 + g * 4) * 96 + l15;
    #pragma unroll
    for (int nt2 = 0; nt2 < 6; ++nt2)
      #pragma unroll
      for (int r = 0; r < 4; ++r)
        ob[r * 96 + nt2 * 16] = pacc[uu][nt2][r] + pb[nt2];
  }
}

extern "C" void kernel_launch(void* const* d_in, const int* in_sizes, int n_in,
                              void* d_out, int out_size, void* d_ws, size_t ws_size,
                              hipStream_t stream) {
  const float* x          = (const float*)d_in[0];
  const float* mask       = (const float*)d_in[1];
  const float* qkv_w      = (const float*)d_in[2];
  const float* qkv_b      = (const float*)d_in[3];
  const float* proj_w     = (const float*)d_in[4];
  const float* proj_b     = (const float*)d_in[5];
  const float* bias_table = (const float*)d_in[6];
  const int*   rel_idx    = (const int*)d_in[7];

  char* ws = (char*)d_ws;
  ushort* qkv_wb    = (ushort*)ws;                    // 288*96*2 = 55296 B
  ushort* proj_wb   = (ushort*)(ws + 55296);          // 96*96*2  = 18432 B
  float*  bias_comb = (float*)(ws + 55296 + 18432);   // 3*64*64*4 = 49152 B
  float*  qkv_bs    = (float*)(ws + 55296 + 18432 + 49152);  // 288*4 = 1152 B

  setup_k<<<194, 256, 0, stream>>>(qkv_w, proj_w, bias_table, rel_idx, qkv_b,
                                   qkv_wb, proj_wb, bias_comb, qkv_bs);
  winattn<<<2048, 512, 0, stream>>>(x, mask, qkv_wb, proj_wb,
                                    bias_comb, qkv_bs, proj_b, (float*)d_out);
}